// Round 7
// baseline (334.086 us; speedup 1.0000x reference)
//
#include <hip/hip_runtime.h>
#include <hip/hip_bf16.h>
#include <math.h>

// Problem constants: x[B=16][T=4096][D=512], W[512][512], v[512]
#define BB 16
#define TT 4096
#define DD 512
#define MM (BB*TT)   // 65536 rows

typedef __bf16 bf16x8 __attribute__((ext_vector_type(8)));
typedef float  f32x4  __attribute__((ext_vector_type(4)));

__device__ inline unsigned short f2bf(float f) {
    unsigned u = __builtin_bit_cast(unsigned, f) + 0x8000u;  // round-half-away
    return (unsigned short)(u >> 16);
}

// pack two fp32 -> two bf16 in one u32 (2 v_add + 1 v_perm)
__device__ inline unsigned pack_bf16x2(float lo, float hi) {
    unsigned u0 = __builtin_bit_cast(unsigned, lo) + 0x8000u;
    unsigned u1 = __builtin_bit_cast(unsigned, hi) + 0x8000u;
    return __builtin_amdgcn_perm(u1, u0, 0x07060302);  // [u1.hi16, u0.hi16]
}

// fast tanh: 1 - 2/(e^{2y}+1).  |y| <~ 2 here, no overflow concerns.
__device__ inline float tanh_fast(float y) {
    float e = __expf(2.0f * y);
    return 1.0f - 2.0f * __builtin_amdgcn_rcpf(e + 1.0f);
}

// ---------------- W fp32 -> Wb bf16, wave-stream fragment order ----------------
// frag id fid = ((h*8 + p)*16 + s)*2 + ni
// lane of frag holds B[k = s*32 + (lane>>4)*8 + j][n = h*256 + p*32 + ni*16 + (lane&15)]
// Each col-QUARTER (n in [wh*128, wh*128+128)) is a single contiguous monotone
// 128 KB stream at offset wh*65536 shorts.
__global__ void wb_kernel(const float* __restrict__ W, unsigned short* __restrict__ Wb) {
    int u = blockIdx.x * 256 + threadIdx.x;   // 0..32767
    int lane = u & 63;
    int fid  = u >> 6;                        // 0..511
    int ni = fid & 1;
    int s  = (fid >> 1) & 15;
    int p  = (fid >> 5) & 7;
    int h  = fid >> 8;
    int n  = h * 256 + p * 32 + ni * 16 + (lane & 15);
    int k0 = s * 32 + (lane >> 4) * 8;
    unsigned short o[8];
    #pragma unroll
    for (int j = 0; j < 8; j++) o[j] = f2bf(W[(size_t)(k0 + j) * DD + n]);
    *(uint4*)(Wb + (size_t)u * 8) = *(uint4*)o;   // coalesced 16 B store
}

// ---------------- Fused GEMM + tanh + v-dot + online-softmax partial pool ----------------
// OCCUPANCY LESSON (R5/R6): VGPR quantum steps at {64,128,256} (m69); a ~100-VGPR
// kernel occupies a 128-reg slot, and the HW cannot co-schedule 4 waves/SIMD x 128
// = the full file when blocks are 8 waves (R6: (512thr,VGPR100) -> 1 block/CU, 21%).
// Fix: make the residency quantum SMALL.  Block = 32 rows, 256 threads (4 waves),
// LDS ~37 KB -> up to 4 blocks/CU by LDS; even at a 3-wave/SIMD register cap we get
// 12 waves/CU (+50% TLP vs the 8-wave ceiling of R3/R6).
// Wave w: the block's 32 rows x col-quarter w; 4 passes of a 32x32 acc tile
// (2x2 16x16x32 frags, full-K accumulate).  Per-wave register shape identical to
// the proven ~100-VGPR kernel (a-ring4, b-ring4, acc 2x2).  B traffic unchanged
// (512 KB per 32-row block = 1 GB total); every wave's quarter-stream is unique.
// A-strip (32x512 bf16 = 32 KB) staged ONCE via NT loads (keep W L2-resident).
// ZERO barriers in the K-loop.
__global__ __launch_bounds__(256, 4) void scorepool_kernel(
        const float* __restrict__ x, const unsigned short* __restrict__ Wb,
        const float* __restrict__ v,
        float* __restrict__ num_ws, float* __restrict__ mz_ws) {
    __shared__ unsigned short As[32 * DD];   // 32 KB
    __shared__ float sbuf[4][32];
    __shared__ float ew[32];
    __shared__ float mzsh[2];
    __shared__ float psum[2][DD];            // 4 KB

    const int tid  = threadIdx.x;
    const int m0   = blockIdx.x * 32;
    const int wid  = tid >> 6;         // 0..3
    const int lane = tid & 63;
    const int l15  = lane & 15;
    const int q    = lane >> 4;
    const int r3   = l15 & 7;
    const int wh   = wid;              // wave col quarter (0..3)

    // ---- Stage A: 32 rows x 512 cols fp32 -> bf16, XOR-swizzled.  NT loads:
    //      x is single-use here; keep it out of L2's LRU so W stays resident.
    #pragma unroll 4
    for (int i = 0; i < 8; i++) {
        int u = i * 256 + tid;           // 0..2047 (16-B output chunk id)
        int r = u >> 6;                  // 64 chunks per row, rows 0..31
        int c = u & 63;
        const float* gp = x + (size_t)(m0 + r) * DD + c * 8;
        f32x4 f0 = __builtin_nontemporal_load((const f32x4*)(gp));
        f32x4 f1 = __builtin_nontemporal_load((const f32x4*)(gp + 4));
        uint4 o;
        o.x = pack_bf16x2(f0.x, f0.y);
        o.y = pack_bf16x2(f0.z, f0.w);
        o.z = pack_bf16x2(f1.x, f1.y);
        o.w = pack_bf16x2(f1.z, f1.w);
        *(uint4*)(&As[r * DD + (c ^ (r & 7)) * 8]) = o;
    }

    // ---- Prime B ring (quarter stream: contiguous 128 KB at wh*65536 shorts).
    const unsigned short* bqp = Wb + (size_t)wh * 65536 + lane * 8;
    bf16x8 b[4][2];
    #pragma unroll
    for (int g = 0; g < 3; g++) {
        b[g][0] = *(const bf16x8*)(bqp);
        b[g][1] = *(const bf16x8*)(bqp + 512);
        bqp += 1024;
    }

    __syncthreads();   // the only barrier before the epilogue

    float vpart[2][4];
    #pragma unroll
    for (int mi = 0; mi < 2; mi++)
        #pragma unroll
        for (int rr = 0; rr < 4; rr++)
            vpart[mi][rr] = 0.f;

    // A-frag: row R = mi*16 + l15, logical chunk c = s*4+q, stored at c^(R&7)
    // (mi*16 == 0 mod 8, so R&7 == l15&7 == r3)
#define A_FRAG(mi, s) (*(const bf16x8*)(&As[((mi)*16 + l15) * DD + ((((s)*4 + q) ^ r3) * 8)]))

    bf16x8 a[4][2];                    // ring-4 over s, 3-step lookahead
    #pragma unroll
    for (int g = 0; g < 3; g++) {
        a[g][0] = A_FRAG(0, g);
        a[g][1] = A_FRAG(1, g);
    }

    #pragma unroll 1
    for (int p = 0; p < 4; p++) {      // 4 passes of 32 cols = this wave's quarter
        f32x4 acc[2][2];
        #pragma unroll
        for (int mi = 0; mi < 2; mi++)
            #pragma unroll
            for (int ni = 0; ni < 2; ni++)
                acc[mi][ni] = (f32x4){0.f, 0.f, 0.f, 0.f};

        #pragma unroll
        for (int s = 0; s < 16; s++) {
            const int ns = (s + 3) & 15;     // pass p+1 reuses same A data (wraps)
            a[(s + 3) & 3][0] = A_FRAG(0, ns);
            a[(s + 3) & 3][1] = A_FRAG(1, ns);
            // B stream, 3-step lookahead (stream padded: tail overrun harmless)
            b[(s + 3) & 3][0] = *(const bf16x8*)(bqp);
            b[(s + 3) & 3][1] = *(const bf16x8*)(bqp + 512);
            bqp += 1024;
            #pragma unroll
            for (int mi = 0; mi < 2; mi++)
                #pragma unroll
                for (int ni = 0; ni < 2; ni++)
                    acc[mi][ni] = __builtin_amdgcn_mfma_f32_16x16x32_bf16(
                        a[s & 3][mi], b[s & 3][ni], acc[mi][ni], 0, 0, 0);
        }

        // per-pass epilogue: tanh + v-dot into per-row partials
        // C/D layout (16x16): col = lane&15, row = q*4 + rr  [m89/m91 verified]
        float vv0 = v[wh * 128 + p * 32 + l15];
        float vv1 = v[wh * 128 + p * 32 + 16 + l15];
        #pragma unroll
        for (int mi = 0; mi < 2; mi++)
            #pragma unroll
            for (int rr = 0; rr < 4; rr++)
                vpart[mi][rr] += tanh_fast(acc[mi][0][rr]) * vv0
                               + tanh_fast(acc[mi][1][rr]) * vv1;
    }
#undef A_FRAG

    // cross-lane reduce over the 16 col-lanes -> per-quarter row partials
    #pragma unroll
    for (int mi = 0; mi < 2; mi++)
        #pragma unroll
        for (int rr = 0; rr < 4; rr++) {
            float sum = vpart[mi][rr];
            sum += __shfl_xor(sum, 1);
            sum += __shfl_xor(sum, 2);
            sum += __shfl_xor(sum, 4);
            sum += __shfl_xor(sum, 8);
            if (l15 == 0)
                sbuf[wh][mi * 16 + q * 4 + rr] = sum;
        }
    __syncthreads();

    // lanes 0..31 of wave 0: row scores -> block max m, e_r, Z (32 rows)
    if (tid < 32) {
        float s = sbuf[0][tid] + sbuf[1][tid] + sbuf[2][tid] + sbuf[3][tid];
        float m = s;
        #pragma unroll
        for (int off = 16; off; off >>= 1) m = fmaxf(m, __shfl_xor(m, off));
        float e = __expf(s - m);
        float z = e;
        #pragma unroll
        for (int off = 16; off; off >>= 1) z += __shfl_xor(z, off);
        ew[tid] = e;
        if (tid == 0) { mzsh[0] = m; mzsh[1] = z; }
    }
    __syncthreads();

    // weighted x-sum from LDS (first 2 waves): thread = (rg row group, cx chunk)
    // num[d] partial = sum_r e_r * xb[r][d]
    const int cx = tid & 63;
    const int rg = tid >> 6;           // 0..1 used
    if (tid < 128) {
        float nacc[8];
        #pragma unroll
        for (int j = 0; j < 8; j++) nacc[j] = 0.f;
        #pragma unroll 4
        for (int i = 0; i < 16; i++) {
            int r = rg * 16 + i;
            uint4 u = *(const uint4*)(&As[r * DD + ((cx ^ (r & 7)) * 8)]);
            float e = ew[r];
            nacc[0] += e * __builtin_bit_cast(float, u.x << 16);
            nacc[1] += e * __builtin_bit_cast(float, u.x & 0xFFFF0000u);
            nacc[2] += e * __builtin_bit_cast(float, u.y << 16);
            nacc[3] += e * __builtin_bit_cast(float, u.y & 0xFFFF0000u);
            nacc[4] += e * __builtin_bit_cast(float, u.z << 16);
            nacc[5] += e * __builtin_bit_cast(float, u.z & 0xFFFF0000u);
            nacc[6] += e * __builtin_bit_cast(float, u.w << 16);
            nacc[7] += e * __builtin_bit_cast(float, u.w & 0xFFFF0000u);
        }
        *(float4*)(&psum[rg][cx * 8])     = *(float4*)(&nacc[0]);
        *(float4*)(&psum[rg][cx * 8 + 4]) = *(float4*)(&nacc[4]);
    }
    __syncthreads();

    if (tid < 128) {
        int c = tid * 4;
        f32x4 f = *(const f32x4*)(&psum[0][c]);
        f += *(const f32x4*)(&psum[1][c]);
        __builtin_nontemporal_store(f, (f32x4*)(num_ws + (size_t)blockIdx.x * DD + c));
    }
    if (tid == 0) {
        mz_ws[2 * blockIdx.x]     = mzsh[0];
        mz_ws[2 * blockIdx.x + 1] = mzsh[1];
    }
}

// ---------------- Combine: merge 128 chunk-partials per batch -> out[b][512] ----------------
__global__ void combine_kernel(const float* __restrict__ num_ws,
                               const float* __restrict__ mz_ws,
                               float* __restrict__ out) {
    __shared__ float red[4];
    __shared__ float red2[4];
    __shared__ float fs[128];
    const int b   = blockIdx.x;
    const int tid = threadIdx.x;

    float m = -1e30f, z = 0.f;
    if (tid < 128) {
        m = mz_ws[(b * 128 + tid) * 2];
        z = mz_ws[(b * 128 + tid) * 2 + 1];
    }
    float M = m;
    #pragma unroll
    for (int off = 32; off; off >>= 1) M = fmaxf(M, __shfl_xor(M, off));
    if ((tid & 63) == 0) red[tid >> 6] = M;
    __syncthreads();
    M = fmaxf(fmaxf(red[0], red[1]), fmaxf(red[2], red[3]));

    float f  = (tid < 128) ? __expf(m - M) : 0.f;
    float fz = f * z;
    #pragma unroll
    for (int off = 32; off; off >>= 1) fz += __shfl_xor(fz, off);
    if ((tid & 63) == 0) red2[tid >> 6] = fz;
    if (tid < 128) fs[tid] = f;
    __syncthreads();
    const float sinv = 1.0f / (red2[0] + red2[1] + red2[2] + red2[3]);

    float a0 = 0.f, a1 = 0.f;
    #pragma unroll 4
    for (int c = 0; c < 128; c++) {
        float fc = fs[c];
        const float* np = num_ws + (size_t)(b * 128 + c) * DD;
        a0 += fc * np[tid];
        a1 += fc * np[tid + 256];
    }
    out[b * DD + tid]       = a0 * sinv;
    out[b * DD + tid + 256] = a1 * sinv;
}

extern "C" void kernel_launch(void* const* d_in, const int* in_sizes, int n_in,
                              void* d_out, int out_size, void* d_ws, size_t ws_size,
                              hipStream_t stream) {
    (void)in_sizes; (void)n_in; (void)out_size; (void)ws_size;
    const float* x = (const float*)d_in[0];
    const float* W = (const float*)d_in[1];
    const float* v = (const float*)d_in[2];
    float* out = (float*)d_out;

    // ws: Wb 512 KB + 16 KB stream-overrun pad | num 2048x512 fp32 (4 MB) | mz 2048x2 fp32
    unsigned short* Wb = (unsigned short*)d_ws;
    float* num_ws      = (float*)((char*)d_ws + 512 * 1024 + 16 * 1024);
    float* mz_ws       = (float*)((char*)d_ws + 512 * 1024 + 16 * 1024 + 4 * 1024 * 1024);

    wb_kernel<<<128, 256, 0, stream>>>(W, Wb);

    scorepool_kernel<<<MM / 32, 256, 0, stream>>>(x, Wb, v, num_ws, mz_ws);

    combine_kernel<<<BB, 256, 0, stream>>>(num_ws, mz_ws, out);
}

// Round 8
// 257.430 us; speedup vs baseline: 1.2978x; 1.2978x over previous
//
#include <hip/hip_runtime.h>
#include <hip/hip_bf16.h>
#include <math.h>

// Problem constants: x[B=16][T=4096][D=512], W[512][512], v[512]
#define BB 16
#define TT 4096
#define DD 512
#define MM (BB*TT)   // 65536 rows

typedef __bf16 bf16x8 __attribute__((ext_vector_type(8)));
typedef float  f32x4  __attribute__((ext_vector_type(4)));

__device__ inline unsigned short f2bf(float f) {
    unsigned u = __builtin_bit_cast(unsigned, f) + 0x8000u;  // round-half-away
    return (unsigned short)(u >> 16);
}

// pack two fp32 -> two bf16 in one u32 (2 v_add + 1 v_perm)
__device__ inline unsigned pack_bf16x2(float lo, float hi) {
    unsigned u0 = __builtin_bit_cast(unsigned, lo) + 0x8000u;
    unsigned u1 = __builtin_bit_cast(unsigned, hi) + 0x8000u;
    return __builtin_amdgcn_perm(u1, u0, 0x07060302);  // [u1.hi16, u0.hi16]
}

// fast tanh: 1 - 2/(e^{2y}+1).  |y| <~ 2 here, no overflow concerns.
__device__ inline float tanh_fast(float y) {
    float e = __expf(2.0f * y);
    return 1.0f - 2.0f * __builtin_amdgcn_rcpf(e + 1.0f);
}

// ---------------- W fp32 -> Wb bf16, wave-stream fragment order ----------------
// frag id fid = ((h*8 + p)*16 + s)*2 + ni
// lane of frag holds B[k = s*32 + (lane>>4)*8 + j][n = h*256 + p*32 + ni*16 + (lane&15)]
// Each col-QUARTER (n in [wh*128, wh*128+128)) is a single contiguous monotone
// 128 KB stream at offset wh*65536 shorts.
__global__ void wb_kernel(const float* __restrict__ W, unsigned short* __restrict__ Wb) {
    int u = blockIdx.x * 256 + threadIdx.x;   // 0..32767
    int lane = u & 63;
    int fid  = u >> 6;                        // 0..511
    int ni = fid & 1;
    int s  = (fid >> 1) & 15;
    int p  = (fid >> 5) & 7;
    int h  = fid >> 8;
    int n  = h * 256 + p * 32 + ni * 16 + (lane & 15);
    int k0 = s * 32 + (lane >> 4) * 8;
    unsigned short o[8];
    #pragma unroll
    for (int j = 0; j < 8; j++) o[j] = f2bf(W[(size_t)(k0 + j) * DD + n]);
    *(uint4*)(Wb + (size_t)u * 8) = *(uint4*)o;   // coalesced 16 B store
}

// ---------------- Fused GEMM + tanh + v-dot + online-softmax partial pool ----------------
// LAUNCH-BOUNDS LAW (5 data points, R0-R7): VGPR compile cap = 256 / (2nd arg),
// independent of block size.  (.,4) -> 64-cap -> spill storm (R5/R7: WRITE 125 MB).
// (.,2) -> 128-cap -> our ~100-reg working set fits.
// OCCUPANCY MODEL: VGPR slots quantize {64,128,256}; R7 proved 32-row/37KB-LDS
// 256-thr blocks co-schedule 4/CU (43%).  At 128-slot, 3 (maybe 4) blocks/CU fit
// -> 12-16 waves/CU, +50-100% TLP over R3's 8.
// Wave w: the block's 32 rows x col-quarter w; 4 passes of a 32x32 acc tile
// (2x2 16x16x32 frags, full-K accumulate).  B streamed via ONE rolling pointer,
// ring-4; A from LDS via ring-4.  ZERO barriers in the K-loop.
// A-strip (32x512 bf16 = 32 KB) staged ONCE via NT loads (keep W L2-resident).
__global__ __launch_bounds__(256, 2) void scorepool_kernel(
        const float* __restrict__ x, const unsigned short* __restrict__ Wb,
        const float* __restrict__ v,
        float* __restrict__ num_ws, float* __restrict__ mz_ws) {
    __shared__ unsigned short As[32 * DD];   // 32 KB
    __shared__ float sbuf[4][32];
    __shared__ float ew[32];
    __shared__ float mzsh[2];
    __shared__ float psum[2][DD];            // 4 KB

    const int tid  = threadIdx.x;
    const int m0   = blockIdx.x * 32;
    const int wid  = tid >> 6;         // 0..3
    const int lane = tid & 63;
    const int l15  = lane & 15;
    const int q    = lane >> 4;
    const int r3   = l15 & 7;
    const int wh   = wid;              // wave col quarter (0..3)

    // ---- Stage A: 32 rows x 512 cols fp32 -> bf16, XOR-swizzled.  NT loads:
    //      x is single-use here; keep it out of L2's LRU so W stays resident.
    #pragma unroll 4
    for (int i = 0; i < 8; i++) {
        int u = i * 256 + tid;           // 0..2047 (16-B output chunk id)
        int r = u >> 6;                  // 64 chunks per row, rows 0..31
        int c = u & 63;
        const float* gp = x + (size_t)(m0 + r) * DD + c * 8;
        f32x4 f0 = __builtin_nontemporal_load((const f32x4*)(gp));
        f32x4 f1 = __builtin_nontemporal_load((const f32x4*)(gp + 4));
        uint4 o;
        o.x = pack_bf16x2(f0.x, f0.y);
        o.y = pack_bf16x2(f0.z, f0.w);
        o.z = pack_bf16x2(f1.x, f1.y);
        o.w = pack_bf16x2(f1.z, f1.w);
        *(uint4*)(&As[r * DD + (c ^ (r & 7)) * 8]) = o;
    }

    // ---- Prime B ring (quarter stream: contiguous 128 KB at wh*65536 shorts).
    const unsigned short* bqp = Wb + (size_t)wh * 65536 + lane * 8;
    bf16x8 b[4][2];
    #pragma unroll
    for (int g = 0; g < 3; g++) {
        b[g][0] = *(const bf16x8*)(bqp);
        b[g][1] = *(const bf16x8*)(bqp + 512);
        bqp += 1024;
    }

    __syncthreads();   // the only barrier before the epilogue

    float vpart[2][4];
    #pragma unroll
    for (int mi = 0; mi < 2; mi++)
        #pragma unroll
        for (int rr = 0; rr < 4; rr++)
            vpart[mi][rr] = 0.f;

    // A-frag: row R = mi*16 + l15, logical chunk c = s*4+q, stored at c^(R&7)
    // (mi*16 == 0 mod 8, so R&7 == l15&7 == r3)
#define A_FRAG(mi, s) (*(const bf16x8*)(&As[((mi)*16 + l15) * DD + ((((s)*4 + q) ^ r3) * 8)]))

    bf16x8 a[4][2];                    // ring-4 over s, 3-step lookahead
    #pragma unroll
    for (int g = 0; g < 3; g++) {
        a[g][0] = A_FRAG(0, g);
        a[g][1] = A_FRAG(1, g);
    }

    #pragma unroll 1
    for (int p = 0; p < 4; p++) {      // 4 passes of 32 cols = this wave's quarter
        f32x4 acc[2][2];
        #pragma unroll
        for (int mi = 0; mi < 2; mi++)
            #pragma unroll
            for (int ni = 0; ni < 2; ni++)
                acc[mi][ni] = (f32x4){0.f, 0.f, 0.f, 0.f};

        #pragma unroll
        for (int s = 0; s < 16; s++) {
            const int ns = (s + 3) & 15;     // pass p+1 reuses same A data (wraps)
            a[(s + 3) & 3][0] = A_FRAG(0, ns);
            a[(s + 3) & 3][1] = A_FRAG(1, ns);
            // B stream, 3-step lookahead (stream padded: tail overrun harmless)
            b[(s + 3) & 3][0] = *(const bf16x8*)(bqp);
            b[(s + 3) & 3][1] = *(const bf16x8*)(bqp + 512);
            bqp += 1024;
            #pragma unroll
            for (int mi = 0; mi < 2; mi++)
                #pragma unroll
                for (int ni = 0; ni < 2; ni++)
                    acc[mi][ni] = __builtin_amdgcn_mfma_f32_16x16x32_bf16(
                        a[s & 3][mi], b[s & 3][ni], acc[mi][ni], 0, 0, 0);
        }

        // per-pass epilogue: tanh + v-dot into per-row partials
        // C/D layout (16x16): col = lane&15, row = q*4 + rr  [m89/m91 verified]
        float vv0 = v[wh * 128 + p * 32 + l15];
        float vv1 = v[wh * 128 + p * 32 + 16 + l15];
        #pragma unroll
        for (int mi = 0; mi < 2; mi++)
            #pragma unroll
            for (int rr = 0; rr < 4; rr++)
                vpart[mi][rr] += tanh_fast(acc[mi][0][rr]) * vv0
                               + tanh_fast(acc[mi][1][rr]) * vv1;
    }
#undef A_FRAG

    // cross-lane reduce over the 16 col-lanes -> per-quarter row partials
    #pragma unroll
    for (int mi = 0; mi < 2; mi++)
        #pragma unroll
        for (int rr = 0; rr < 4; rr++) {
            float sum = vpart[mi][rr];
            sum += __shfl_xor(sum, 1);
            sum += __shfl_xor(sum, 2);
            sum += __shfl_xor(sum, 4);
            sum += __shfl_xor(sum, 8);
            if (l15 == 0)
                sbuf[wh][mi * 16 + q * 4 + rr] = sum;
        }
    __syncthreads();

    // lanes 0..31 of wave 0: row scores -> block max m, e_r, Z (32 rows)
    if (tid < 32) {
        float s = sbuf[0][tid] + sbuf[1][tid] + sbuf[2][tid] + sbuf[3][tid];
        float m = s;
        #pragma unroll
        for (int off = 16; off; off >>= 1) m = fmaxf(m, __shfl_xor(m, off));
        float e = __expf(s - m);
        float z = e;
        #pragma unroll
        for (int off = 16; off; off >>= 1) z += __shfl_xor(z, off);
        ew[tid] = e;
        if (tid == 0) { mzsh[0] = m; mzsh[1] = z; }
    }
    __syncthreads();

    // weighted x-sum from LDS (first 2 waves): thread = (rg row group, cx chunk)
    // num[d] partial = sum_r e_r * xb[r][d]
    const int cx = tid & 63;
    const int rg = tid >> 6;           // 0..1 used
    if (tid < 128) {
        float nacc[8];
        #pragma unroll
        for (int j = 0; j < 8; j++) nacc[j] = 0.f;
        #pragma unroll 4
        for (int i = 0; i < 16; i++) {
            int r = rg * 16 + i;
            uint4 u = *(const uint4*)(&As[r * DD + ((cx ^ (r & 7)) * 8)]);
            float e = ew[r];
            nacc[0] += e * __builtin_bit_cast(float, u.x << 16);
            nacc[1] += e * __builtin_bit_cast(float, u.x & 0xFFFF0000u);
            nacc[2] += e * __builtin_bit_cast(float, u.y << 16);
            nacc[3] += e * __builtin_bit_cast(float, u.y & 0xFFFF0000u);
            nacc[4] += e * __builtin_bit_cast(float, u.z << 16);
            nacc[5] += e * __builtin_bit_cast(float, u.z & 0xFFFF0000u);
            nacc[6] += e * __builtin_bit_cast(float, u.w << 16);
            nacc[7] += e * __builtin_bit_cast(float, u.w & 0xFFFF0000u);
        }
        *(float4*)(&psum[rg][cx * 8])     = *(float4*)(&nacc[0]);
        *(float4*)(&psum[rg][cx * 8 + 4]) = *(float4*)(&nacc[4]);
    }
    __syncthreads();

    if (tid < 128) {
        int c = tid * 4;
        f32x4 f = *(const f32x4*)(&psum[0][c]);
        f += *(const f32x4*)(&psum[1][c]);
        __builtin_nontemporal_store(f, (f32x4*)(num_ws + (size_t)blockIdx.x * DD + c));
    }
    if (tid == 0) {
        mz_ws[2 * blockIdx.x]     = mzsh[0];
        mz_ws[2 * blockIdx.x + 1] = mzsh[1];
    }
}

// ---------------- Combine: merge 128 chunk-partials per batch -> out[b][512] ----------------
__global__ void combine_kernel(const float* __restrict__ num_ws,
                               const float* __restrict__ mz_ws,
                               float* __restrict__ out) {
    __shared__ float red[4];
    __shared__ float red2[4];
    __shared__ float fs[128];
    const int b   = blockIdx.x;
    const int tid = threadIdx.x;

    float m = -1e30f, z = 0.f;
    if (tid < 128) {
        m = mz_ws[(b * 128 + tid) * 2];
        z = mz_ws[(b * 128 + tid) * 2 + 1];
    }
    float M = m;
    #pragma unroll
    for (int off = 32; off; off >>= 1) M = fmaxf(M, __shfl_xor(M, off));
    if ((tid & 63) == 0) red[tid >> 6] = M;
    __syncthreads();
    M = fmaxf(fmaxf(red[0], red[1]), fmaxf(red[2], red[3]));

    float f  = (tid < 128) ? __expf(m - M) : 0.f;
    float fz = f * z;
    #pragma unroll
    for (int off = 32; off; off >>= 1) fz += __shfl_xor(fz, off);
    if ((tid & 63) == 0) red2[tid >> 6] = fz;
    if (tid < 128) fs[tid] = f;
    __syncthreads();
    const float sinv = 1.0f / (red2[0] + red2[1] + red2[2] + red2[3]);

    float a0 = 0.f, a1 = 0.f;
    #pragma unroll 4
    for (int c = 0; c < 128; c++) {
        float fc = fs[c];
        const float* np = num_ws + (size_t)(b * 128 + c) * DD;
        a0 += fc * np[tid];
        a1 += fc * np[tid + 256];
    }
    out[b * DD + tid]       = a0 * sinv;
    out[b * DD + tid + 256] = a1 * sinv;
}

extern "C" void kernel_launch(void* const* d_in, const int* in_sizes, int n_in,
                              void* d_out, int out_size, void* d_ws, size_t ws_size,
                              hipStream_t stream) {
    (void)in_sizes; (void)n_in; (void)out_size; (void)ws_size;
    const float* x = (const float*)d_in[0];
    const float* W = (const float*)d_in[1];
    const float* v = (const float*)d_in[2];
    float* out = (float*)d_out;

    // ws: Wb 512 KB + 16 KB stream-overrun pad | num 2048x512 fp32 (4 MB) | mz 2048x2 fp32
    unsigned short* Wb = (unsigned short*)d_ws;
    float* num_ws      = (float*)((char*)d_ws + 512 * 1024 + 16 * 1024);
    float* mz_ws       = (float*)((char*)d_ws + 512 * 1024 + 16 * 1024 + 4 * 1024 * 1024);

    wb_kernel<<<128, 256, 0, stream>>>(W, Wb);

    scorepool_kernel<<<MM / 32, 256, 0, stream>>>(x, Wb, v, num_ws, mz_ws);

    combine_kernel<<<BB, 256, 0, stream>>>(num_ws, mz_ws, out);
}